// Round 4
// baseline (581.833 us; speedup 1.0000x reference)
//
#include <hip/hip_runtime.h>
#include <cstdint>
#include <cstddef>

#define T_LEN 8192
#define BATCH 64
#define HID   10
#define CH    66
#define EEG   64
#define SM_STRIDE 8384   // 192-entry zero pad + 8192 live, per batch (16B-aligned stride)
#define CHK   512        // live t per block (was 1024): halves LDS -> 4 blocks/CU
#define TS2   548        // tile stride floats: 32 warm + 512 live + 4 pad; 548*4B rows are
                         // 16B-aligned; row-start bank = 4h mod 32 -> <=2-way alias (free)

// ---------------------------------------------------------------------------
// K12: FUSED front projection + front LIF, v2 (latency-hiding rebuild).
// Round-3 evidence: 79.5 us @ 881 GB/s, VALUBusy 19.7% -> 80% all-wave stall
// (global-load latency, 2 waves/SIMD, ~4 loads in flight). Changes:
//  - grid (16,64), chunk=512, LDS 24.5 KB -> 4 blocks/CU = 16 waves/CU.
//  - Phase A: float2 groups (272, all threads active), explicit 8-deep load
//    ring (static indices) -> 8 independent 512B loads in flight per wave.
//  - wf padded [64][12], fetched as float4+float4+float2 (3 LDS reads/chan).
//  - Phase B: 160-step scans (halved), 3-deep LDS float4 prefetch ring.
// Accumulation order over c unchanged -> y, smask bit-identical to round 3.
// ---------------------------------------------------------------------------
__global__ __launch_bounds__(256) void k_front_lif(
    const float* __restrict__ x, const float* __restrict__ wf_g,
    const float* __restrict__ bf_g, unsigned short* __restrict__ smask,
    float* __restrict__ out) {
    __shared__ float wf[EEG][12];    // wf[c][h], h-padded to 12
    __shared__ float bf[HID];
    __shared__ float yt[HID][TS2];   // tile index k <-> t = t0 - 32 + k
    int tid = threadIdx.x;
    for (int i = tid; i < EEG * 12; i += 256) {
        int c = i / 12, h = i - 12 * (i / 12);
        wf[c][h] = (h < HID) ? wf_g[h * EEG + c] : 0.f;   // w_front layout (H, C)
    }
    if (tid < HID) bf[tid] = bf_g[tid];

    int chunk = blockIdx.x;          // 0..15 (512 live t each)
    int b     = blockIdx.y;          // 0..63
    if (chunk == 0) {                // zero the 192-entry smask pad for this batch
        for (int i = tid; i < 96; i += 256)
            ((unsigned*)(smask + (size_t)b * SM_STRIDE))[i] = 0u;
        if (b == 0)                  // fold the out-memset dispatch in here
            for (int i = tid; i < BATCH * 2; i += 256) out[i] = 0.f;
    }
    __syncthreads();

    // ---- Phase A: projection into LDS tile (c-ascending FMA chain, same
    //      accumulation order as before -> bit-identical y) ----
    int t0 = chunk * CHK;
    const float* xb = x + ((size_t)b * CH + 1) * T_LEN;   // skip aud channel 0
    for (int g = tid; g < 272; g += 256) {                // 272 float2 groups = 544 t
        int t = t0 - 32 + 2 * g;
        if (t < 0) continue;         // chunk-0 head: region never read by LIF
        const float* xp = xb + t;
        float2 xv[8];
#pragma unroll
        for (int c = 0; c < 8; ++c) xv[c] = *(const float2*)(xp + (size_t)c * T_LEN);
        float a0[HID], a1[HID];
#pragma unroll
        for (int h = 0; h < HID; ++h) { a0[h] = bf[h]; a1[h] = bf[h]; }
#pragma unroll
        for (int c = 0; c < EEG; ++c) {
            float2 xc = xv[c & 7];
            if (c + 8 < EEG)                     // compile-time predicate (full unroll)
                xv[c & 7] = *(const float2*)(xp + (size_t)(c + 8) * T_LEN);
            float4 w0 = *(const float4*)&wf[c][0];
            float4 w1 = *(const float4*)&wf[c][4];
            float2 w2 = *(const float2*)&wf[c][8];
            a0[0] = fmaf(xc.x, w0.x, a0[0]);  a1[0] = fmaf(xc.y, w0.x, a1[0]);
            a0[1] = fmaf(xc.x, w0.y, a0[1]);  a1[1] = fmaf(xc.y, w0.y, a1[1]);
            a0[2] = fmaf(xc.x, w0.z, a0[2]);  a1[2] = fmaf(xc.y, w0.z, a1[2]);
            a0[3] = fmaf(xc.x, w0.w, a0[3]);  a1[3] = fmaf(xc.y, w0.w, a1[3]);
            a0[4] = fmaf(xc.x, w1.x, a0[4]);  a1[4] = fmaf(xc.y, w1.x, a1[4]);
            a0[5] = fmaf(xc.x, w1.y, a0[5]);  a1[5] = fmaf(xc.y, w1.y, a1[5]);
            a0[6] = fmaf(xc.x, w1.z, a0[6]);  a1[6] = fmaf(xc.y, w1.z, a1[6]);
            a0[7] = fmaf(xc.x, w1.w, a0[7]);  a1[7] = fmaf(xc.y, w1.w, a1[7]);
            a0[8] = fmaf(xc.x, w2.x, a0[8]);  a1[8] = fmaf(xc.y, w2.x, a1[8]);
            a0[9] = fmaf(xc.x, w2.y, a0[9]);  a1[9] = fmaf(xc.y, w2.y, a1[9]);
        }
        int k = 2 * g;
#pragma unroll
        for (int h = 0; h < HID; ++h)
            *(float2*)&yt[h][k] = make_float2(a0[h], a1[h]);
    }
    __syncthreads();

    // ---- Phase B: LIF scan, one 128-step quarter per wave, 32-step warm ----
    int w    = tid >> 6;             // wave 0..3
    int lane = tid & 63;
    int h    = lane & 15;
    int hh   = h < HID ? h : HID - 1;  // spare lanes duplicate h=9 (bits masked)

    int kliv = 32 + 128 * w;                       // first live tile index
    int wl   = (chunk == 0 && w == 0) ? 0 : 32;    // warm length
    int ks   = kliv - wl;                          // scan start (mult of 4)
    int nf   = (128 + wl) >> 2;                    // float4 steps (32 or 40)
    const float4* yrow = (const float4*)&yt[hh][0];
    int base = ks >> 2;

    unsigned short* smb = smask + (size_t)b * SM_STRIDE + 192 + t0 + 128 * w;
    float u = 0.f, o = 0.f;
    float4 A = yrow[base], B = yrow[base + 1], C = yrow[base + 2];
    for (int f = 0; f < nf; ++f) {
        int nx = f + 3; if (nx > nf - 1) nx = nf - 1;
        float4 D = yrow[base + nx];
        float vv[4] = {A.x, A.y, A.z, A.w};
        int kb = ks + 4 * f;
#pragma unroll
        for (int k2 = 0; k2 < 4; ++k2) {
            u = (o > 0.5f) ? vv[k2] : fmaf(0.25f, u, vv[k2]);   // 0.25*u exact
            bool sp = (u > 0.2f);
            o = sp ? 1.0f : 0.0f;
            unsigned long long bal = __ballot(sp);
            int k = kb + k2;
            if (k >= kliv && h == 0)
                smb[k - kliv] = (unsigned short)(bal & 0x3FFull);
        }
        A = B; B = C; C = D;
    }
}

// ---------------------------------------------------------------------------
// K3: LSNN scan + classifier. 128 chunks x 64 live steps, warm 192 (zero pad
// -> uniform 256-step loop). Direct 1024x22 subset-sum table D (88 KB LDS):
// every rec/X/P lookup is a single ds_read_b32. Unchanged from round 2
// (verified); kept stable this round for attribution.
// ---------------------------------------------------------------------------
__global__ __launch_bounds__(512) void k_lsnn(
    const unsigned short* __restrict__ smask,
    const float* __restrict__ w_in, const float* __restrict__ w_rec,
    const float* __restrict__ w_cls, const float* __restrict__ b_cls,
    float* __restrict__ out) {
    extern __shared__ float LDSBUF[];
    float* T = LDSBUF;          // [1536]: [hi*768 + m*24 + role], roles 0-9 w_in,
                                //         10-11 w_cls, 12-21 w_rec, 22-23 zero
    float* D = LDSBUF + 1536;   // [1024*22]: D[z*22+role] = full 10-bit subset sum
    int tid = threadIdx.x;
    for (int i = tid; i < 1536; i += 512) {
        int hi = i / 768;
        int rem = i - hi * 768;
        int m = rem / 24, role = rem - m * 24;
        float s = 0.f;
        if (role < 22) {
            const float* wrow = (role < 10) ? (w_in + role * HID)
                              : (role < 12) ? (w_cls + (role - 10) * HID)
                                            : (w_rec + (role - 12) * HID);
#pragma unroll
            for (int j = 0; j < 5; ++j)
                if (m & (1u << j)) s += wrow[hi * 5 + j];
        }
        T[i] = s;
    }
    __syncthreads();
    for (int i = tid; i < 1024 * 22; i += 512) {
        int z = i / 22, role = i - z * 22;
        D[i] = T[(z & 31) * 24 + role] + T[768 + (z >> 5) * 24 + role];
    }
    __syncthreads();

    int lane = tid & 63;
    int q = lane >> 4;                 // unit-in-wave 0..3
    int r = lane & 15;                 // role: 0..9 hidden, 10..11 cls, 12..15 shadow
    int rr = r < 12 ? r : 11;          // X/P table role (shadows duplicate 11)
    int rrec = 12 + (r < HID ? r : 9); // rec table role (cls/shadows dup row 9, unused)
    int shq = q * 16;
    int id = blockIdx.x * 32 + (tid >> 4);   // 256*32 = 8192 units, no tail
    int b = id >> 7, chunk = id & 127;

    float bcl = (r == 10 || r == 11) ? b_cls[r - HID] : 0.f;

    const unsigned short* sm = smask + (size_t)b * SM_STRIDE + (size_t)chunk * 64;

    auto xlook = [&](const uint4& mv, float* X) {
        unsigned hw[8] = { mv.x & 0x3FFu, (mv.x >> 16) & 0x3FFu,
                           mv.y & 0x3FFu, (mv.y >> 16) & 0x3FFu,
                           mv.z & 0x3FFu, (mv.z >> 16) & 0x3FFu,
                           mv.w & 0x3FFu, (mv.w >> 16) & 0x3FFu };
#pragma unroll
        for (int u = 0; u < 8; ++u)
            X[u] = D[hw[u] * 22 + rr];
    };

    // 4-deep mask prefetch ring
    uint4 mB = *(const uint4*)(sm + 8);
    uint4 mC = *(const uint4*)(sm + 16);
    uint4 mD = *(const uint4*)(sm + 24);
    float Xc[8], Xn[8], Pc[8], Pn[8];
    { uint4 m0 = *(const uint4*)(sm); xlook(m0, Xc); }
#pragma unroll
    for (int u = 0; u < 8; ++u) { Pc[u] = 0.f; Pn[u] = 0.f; }

    float v = 0.f, cur = 0.f;
    unsigned zmask = 0;
    float uc = 0.f, oc = 0.f, accs = 0.f;

    for (int gr = 0; gr < 32; ++gr) {
        int nb = gr + 4; if (nb > 31) nb = 31;
        uint4 mE = *(const uint4*)(sm + (size_t)nb * 8);
        xlook(mB, Xn);                  // x_in for next group (off-chain, 3 groups slack)
        unsigned zs[8];
#pragma unroll
        for (int u = 0; u < 8; ++u) {
            // rec dot: ONE ds_read from the direct table
            float rec = D[zmask * 22 + rrec];
            float ij = (cur + Xc[u]) + rec;
            float vd = v + 0.1f * (ij - v);     // bit-exact form (matches reference)
            cur = ij - 0.2f * ij;               // bit-exact form
            bool zb = vd > 0.2f;                // b_dec == VTH exactly
            unsigned long long bal = __ballot(zb);
            v = zb ? 0.f : vd;
            zmask = (unsigned)(bal >> shq) & 0x3FFu;
            zs[u] = zmask;
        }
        if (gr >= 21) {                        // classifier-input lookups (batched)
#pragma unroll
            for (int u = 0; u < 8; ++u)
                Pn[u] = D[zs[u] * 22 + rr];
        }
        if (gr >= 22) {                        // classifier LIF for group gr-1
            bool in = (gr >= 25);              // live groups are 24..31
#pragma unroll
            for (int u = 0; u < 8; ++u) {
                float ci = Pc[u] + bcl;
                uc = (oc > 0.5f) ? ci : fmaf(0.25f, uc, ci);
                oc = (uc > 0.2f) ? 1.f : 0.f;
                if (in) accs += oc;
            }
        }
#pragma unroll
        for (int u = 0; u < 8; ++u) { Xc[u] = Xn[u]; Pc[u] = Pn[u]; }
        mB = mC; mC = mD; mD = mE;
    }
    // epilogue: classifier for group 31 (live)
#pragma unroll
    for (int u = 0; u < 8; ++u) {
        float ci = Pc[u] + bcl;
        uc = (oc > 0.5f) ? ci : fmaf(0.25f, uc, ci);
        oc = (uc > 0.2f) ? 1.f : 0.f;
        accs += oc;
    }
    if (r == 10 || r == 11)
        atomicAdd(&out[b * 2 + (r - 10)], accs * (1.0f / 8192.0f));
}

// ---------------------------------------------------------------------------
extern "C" void kernel_launch(void* const* d_in, const int* in_sizes, int n_in,
                              void* d_out, int out_size, void* d_ws, size_t ws_size,
                              hipStream_t stream) {
    const float* x       = (const float*)d_in[0];
    const float* w_front = (const float*)d_in[1];
    const float* b_front = (const float*)d_in[2];
    const float* w_in    = (const float*)d_in[3];
    const float* w_rec   = (const float*)d_in[4];
    const float* w_cls   = (const float*)d_in[5];
    const float* b_cls   = (const float*)d_in[6];
    float* out = (float*)d_out;

    unsigned short* smask = (unsigned short*)d_ws;   // 64*8384*2 = 1.07 MB

    k_front_lif<<<dim3(16, BATCH), 256, 0, stream>>>(x, w_front, b_front, smask, out);
    k_lsnn<<<dim3(256), 512, (1536 + 1024 * 22) * sizeof(float), stream>>>(
        smask, w_in, w_rec, w_cls, b_cls, out);
}

// Round 5
// 266.680 us; speedup vs baseline: 2.1818x; 2.1818x over previous
//
#include <hip/hip_runtime.h>
#include <cstdint>
#include <cstddef>

#define T_LEN 8192
#define BATCH 64
#define HID   10
#define CH    66
#define EEG   64
#define SM_STRIDE 8384   // 192-entry zero pad + 8192 live, per batch (16B-aligned stride)
#define CHK   512        // live t per block: LDS 24.5 KB -> 4 blocks/CU (16 waves/CU)
#define TS2   548        // tile stride floats: 32 warm + 512 live + 4 pad; 16B-aligned rows

// ---------------------------------------------------------------------------
// K12: FUSED front projection + front LIF, v3.
// Round-4 lesson: the hand-rolled 8-deep float2 ring + full 64-iter unroll
// spilled (VGPR 256, 167 MB scratch writes, 390 us). REVERT Phase A to the
// round-3 code that compiled to 68 VGPR, and get latency hiding from
// OCCUPANCY instead: chunk 1024->512 halves LDS (24.5 KB) and doubles the
// grid to 1024 blocks = 4 blocks/CU = 16 waves/CU (the VGPR-68 cap).
// __launch_bounds__(256,4) caps VGPR at 128 so regalloc can never blow up.
// Same c-ascending FMA chain -> y, smask bit-identical.
// ---------------------------------------------------------------------------
__global__ __launch_bounds__(256, 4) void k_front_lif(
    const float* __restrict__ x, const float* __restrict__ wf_g,
    const float* __restrict__ bf_g, unsigned short* __restrict__ smask,
    float* __restrict__ out) {
    __shared__ float wf[EEG][HID];   // wf[c][h]
    __shared__ float bf[HID];
    __shared__ float yt[HID][TS2];   // tile index k <-> t = t0 - 32 + k
    int tid = threadIdx.x;
    for (int i = tid; i < EEG * HID; i += 256) {
        int h = i / EEG, c = i % EEG;      // w_front layout (H, C)
        wf[c][h] = wf_g[i];
    }
    if (tid < HID) bf[tid] = bf_g[tid];

    int chunk = blockIdx.x;          // 0..15 (512 live t each)
    int b     = blockIdx.y;          // 0..63
    if (chunk == 0) {                // zero the 192-entry smask pad for this batch
        for (int i = tid; i < 96; i += 256)
            ((unsigned*)(smask + (size_t)b * SM_STRIDE))[i] = 0u;
        if (b == 0)                  // fold the out-memset dispatch in here
            for (int i = tid; i < BATCH * 2; i += 256) out[i] = 0.f;
    }
    __syncthreads();

    // ---- Phase A: projection into LDS tile (round-3 code, 136 float4 groups;
    //      c-ascending FMA chain -> bit-identical y) ----
    int t0 = chunk * CHK;
    const float* xb = x + ((size_t)b * CH + 1) * T_LEN;   // skip aud channel 0
    for (int g = tid; g < 136; g += 256) {                // 136 float4 groups = 544 t
        int t = t0 - 32 + 4 * g;
        if (t < 0) continue;         // chunk-0 head: region never read by LIF
        float acc[4][HID];
#pragma unroll
        for (int j = 0; j < 4; ++j)
#pragma unroll
            for (int h = 0; h < HID; ++h) acc[j][h] = bf[h];
        const float* xp = xb + t;
#pragma unroll 4
        for (int c = 0; c < EEG; ++c) {
            float4 xv = *(const float4*)(xp + (size_t)c * T_LEN);
#pragma unroll
            for (int h = 0; h < HID; ++h) {
                float w = wf[c][h];
                acc[0][h] = fmaf(xv.x, w, acc[0][h]);
                acc[1][h] = fmaf(xv.y, w, acc[1][h]);
                acc[2][h] = fmaf(xv.z, w, acc[2][h]);
                acc[3][h] = fmaf(xv.w, w, acc[3][h]);
            }
        }
        int k = 4 * g;
#pragma unroll
        for (int h = 0; h < HID; ++h)
            *(float4*)&yt[h][k] =
                make_float4(acc[0][h], acc[1][h], acc[2][h], acc[3][h]);
    }
    __syncthreads();

    // ---- Phase B: LIF scan, one 128-step quarter per wave, 32-step warm ----
    int w    = tid >> 6;             // wave 0..3
    int lane = tid & 63;
    int h    = lane & 15;
    int hh   = h < HID ? h : HID - 1;  // spare lanes duplicate h=9 (bits masked)

    int kliv = 32 + 128 * w;                       // first live tile index
    int wl   = (chunk == 0 && w == 0) ? 0 : 32;    // warm length
    int ks   = kliv - wl;                          // scan start (mult of 4)
    int nf   = (128 + wl) >> 2;                    // float4 steps (32 or 40)
    const float4* yrow = (const float4*)&yt[hh][0];
    int base = ks >> 2;

    unsigned short* smb = smask + (size_t)b * SM_STRIDE + 192 + t0 + 128 * w;
    float u = 0.f, o = 0.f;
    float4 A = yrow[base], B = yrow[base + 1], C = yrow[base + 2];
    for (int f = 0; f < nf; ++f) {
        int nx = f + 3; if (nx > nf - 1) nx = nf - 1;
        float4 D = yrow[base + nx];
        float vv[4] = {A.x, A.y, A.z, A.w};
        int kb = ks + 4 * f;
#pragma unroll
        for (int k2 = 0; k2 < 4; ++k2) {
            u = (o > 0.5f) ? vv[k2] : fmaf(0.25f, u, vv[k2]);   // 0.25*u exact
            bool sp = (u > 0.2f);
            o = sp ? 1.0f : 0.0f;
            unsigned long long bal = __ballot(sp);
            int k = kb + k2;
            if (k >= kliv && h == 0)
                smb[k - kliv] = (unsigned short)(bal & 0x3FFull);
        }
        A = B; B = C; C = D;
    }
}

// ---------------------------------------------------------------------------
// K3: LSNN scan + classifier. 128 chunks x 64 live steps, warm 192 (zero pad
// -> uniform 256-step loop). Direct 1024x22 subset-sum table D (88 KB LDS):
// every rec/X/P lookup is a single ds_read_b32. Unchanged (verified, at its
// structural latency floor ~15 us); kept stable for attribution.
// ---------------------------------------------------------------------------
__global__ __launch_bounds__(512) void k_lsnn(
    const unsigned short* __restrict__ smask,
    const float* __restrict__ w_in, const float* __restrict__ w_rec,
    const float* __restrict__ w_cls, const float* __restrict__ b_cls,
    float* __restrict__ out) {
    extern __shared__ float LDSBUF[];
    float* T = LDSBUF;          // [1536]: [hi*768 + m*24 + role], roles 0-9 w_in,
                                //         10-11 w_cls, 12-21 w_rec, 22-23 zero
    float* D = LDSBUF + 1536;   // [1024*22]: D[z*22+role] = full 10-bit subset sum
    int tid = threadIdx.x;
    for (int i = tid; i < 1536; i += 512) {
        int hi = i / 768;
        int rem = i - hi * 768;
        int m = rem / 24, role = rem - m * 24;
        float s = 0.f;
        if (role < 22) {
            const float* wrow = (role < 10) ? (w_in + role * HID)
                              : (role < 12) ? (w_cls + (role - 10) * HID)
                                            : (w_rec + (role - 12) * HID);
#pragma unroll
            for (int j = 0; j < 5; ++j)
                if (m & (1u << j)) s += wrow[hi * 5 + j];
        }
        T[i] = s;
    }
    __syncthreads();
    for (int i = tid; i < 1024 * 22; i += 512) {
        int z = i / 22, role = i - z * 22;
        D[i] = T[(z & 31) * 24 + role] + T[768 + (z >> 5) * 24 + role];
    }
    __syncthreads();

    int lane = tid & 63;
    int q = lane >> 4;                 // unit-in-wave 0..3
    int r = lane & 15;                 // role: 0..9 hidden, 10..11 cls, 12..15 shadow
    int rr = r < 12 ? r : 11;          // X/P table role (shadows duplicate 11)
    int rrec = 12 + (r < HID ? r : 9); // rec table role (cls/shadows dup row 9, unused)
    int shq = q * 16;
    int id = blockIdx.x * 32 + (tid >> 4);   // 256*32 = 8192 units, no tail
    int b = id >> 7, chunk = id & 127;

    float bcl = (r == 10 || r == 11) ? b_cls[r - HID] : 0.f;

    const unsigned short* sm = smask + (size_t)b * SM_STRIDE + (size_t)chunk * 64;

    auto xlook = [&](const uint4& mv, float* X) {
        unsigned hw[8] = { mv.x & 0x3FFu, (mv.x >> 16) & 0x3FFu,
                           mv.y & 0x3FFu, (mv.y >> 16) & 0x3FFu,
                           mv.z & 0x3FFu, (mv.z >> 16) & 0x3FFu,
                           mv.w & 0x3FFu, (mv.w >> 16) & 0x3FFu };
#pragma unroll
        for (int u = 0; u < 8; ++u)
            X[u] = D[hw[u] * 22 + rr];
    };

    // 4-deep mask prefetch ring
    uint4 mB = *(const uint4*)(sm + 8);
    uint4 mC = *(const uint4*)(sm + 16);
    uint4 mD = *(const uint4*)(sm + 24);
    float Xc[8], Xn[8], Pc[8], Pn[8];
    { uint4 m0 = *(const uint4*)(sm); xlook(m0, Xc); }
#pragma unroll
    for (int u = 0; u < 8; ++u) { Pc[u] = 0.f; Pn[u] = 0.f; }

    float v = 0.f, cur = 0.f;
    unsigned zmask = 0;
    float uc = 0.f, oc = 0.f, accs = 0.f;

    for (int gr = 0; gr < 32; ++gr) {
        int nb = gr + 4; if (nb > 31) nb = 31;
        uint4 mE = *(const uint4*)(sm + (size_t)nb * 8);
        xlook(mB, Xn);                  // x_in for next group (off-chain, 3 groups slack)
        unsigned zs[8];
#pragma unroll
        for (int u = 0; u < 8; ++u) {
            // rec dot: ONE ds_read from the direct table
            float rec = D[zmask * 22 + rrec];
            float ij = (cur + Xc[u]) + rec;
            float vd = v + 0.1f * (ij - v);     // bit-exact form (matches reference)
            cur = ij - 0.2f * ij;               // bit-exact form
            bool zb = vd > 0.2f;                // b_dec == VTH exactly
            unsigned long long bal = __ballot(zb);
            v = zb ? 0.f : vd;
            zmask = (unsigned)(bal >> shq) & 0x3FFu;
            zs[u] = zmask;
        }
        if (gr >= 21) {                        // classifier-input lookups (batched)
#pragma unroll
            for (int u = 0; u < 8; ++u)
                Pn[u] = D[zs[u] * 22 + rr];
        }
        if (gr >= 22) {                        // classifier LIF for group gr-1
            bool in = (gr >= 25);              // live groups are 24..31
#pragma unroll
            for (int u = 0; u < 8; ++u) {
                float ci = Pc[u] + bcl;
                uc = (oc > 0.5f) ? ci : fmaf(0.25f, uc, ci);
                oc = (uc > 0.2f) ? 1.f : 0.f;
                if (in) accs += oc;
            }
        }
#pragma unroll
        for (int u = 0; u < 8; ++u) { Xc[u] = Xn[u]; Pc[u] = Pn[u]; }
        mB = mC; mC = mD; mD = mE;
    }
    // epilogue: classifier for group 31 (live)
#pragma unroll
    for (int u = 0; u < 8; ++u) {
        float ci = Pc[u] + bcl;
        uc = (oc > 0.5f) ? ci : fmaf(0.25f, uc, ci);
        oc = (uc > 0.2f) ? 1.f : 0.f;
        accs += oc;
    }
    if (r == 10 || r == 11)
        atomicAdd(&out[b * 2 + (r - 10)], accs * (1.0f / 8192.0f));
}

// ---------------------------------------------------------------------------
extern "C" void kernel_launch(void* const* d_in, const int* in_sizes, int n_in,
                              void* d_out, int out_size, void* d_ws, size_t ws_size,
                              hipStream_t stream) {
    const float* x       = (const float*)d_in[0];
    const float* w_front = (const float*)d_in[1];
    const float* b_front = (const float*)d_in[2];
    const float* w_in    = (const float*)d_in[3];
    const float* w_rec   = (const float*)d_in[4];
    const float* w_cls   = (const float*)d_in[5];
    const float* b_cls   = (const float*)d_in[6];
    float* out = (float*)d_out;

    unsigned short* smask = (unsigned short*)d_ws;   // 64*8384*2 = 1.07 MB

    k_front_lif<<<dim3(16, BATCH), 256, 0, stream>>>(x, w_front, b_front, smask, out);
    k_lsnn<<<dim3(256), 512, (1536 + 1024 * 22) * sizeof(float), stream>>>(
        smask, w_in, w_rec, w_cls, b_cls, out);
}